// Round 4
// baseline (148.972 us; speedup 1.0000x reference)
//
#include <hip/hip_runtime.h>
#include <hip/hip_bf16.h>

// Problem constants (from reference)
#define NN    4096
#define DD    256
#define HH    4
#define DHH   64
#define EDGES 131072
#define CAP   128           // per-row edge-list capacity; deg ~ Poisson(32), P(>128) < 1e-40
#define LRELU_ALPHA 0.2f

typedef __hip_bfloat16 bf16;

// dtypes (T1, validated against all 3 failed rounds):
//   ALL float inputs are fp32 (round-1 bf16-bitcast read -> NaN proves it),
//   edge_index int32, and the OUTPUT is fp32 too (reference returns fp32;
//   harness doc: "bfloat16 -> __hip_bfloat16*, else float*"). Rounds 2-3
//   wrote bf16 into the float buffer -> scrambled read-back, absmax ~10.18
//   (= out-scale exponent from high half + mantissa noise; second half of
//   the buffer left at memset-0) -- exactly what was measured.
//
// ws layout, 3.14 MB total:
//   hb    [N][H][DH] bf16   @ 0         (2 MB)
//   esrc  [N][H]     f32    @ 2097152   (64 KB)
//   edst  [N][H]     f32    @ 2162688   (64 KB)
//   cnt   [N]        int    @ 2228224   (16 KB)   <- memset 0
//   lists [N][CAP]   ushort @ 2244608   (1 MB)

// ---------------------------------------------------------------------------
// Kernel A: h[n,h,dh] = sum_d x[n,d] W[h,d,dh]  (fp32 acc, stored bf16)
//           esrc[n,h] = sum_dh h*a_src[h,dh] ; edst likewise (fp32, from regs)
// Block = node; wave = head; lane = dh.
// ---------------------------------------------------------------------------
__global__ __launch_bounds__(256) void hproj_kernel(
    const float* __restrict__ x, const float* __restrict__ W,
    const float* __restrict__ a_src, const float* __restrict__ a_dst,
    bf16* __restrict__ hb, float* __restrict__ esrc, float* __restrict__ edst)
{
    __shared__ float xs[DD];
    const int i = blockIdx.x, t = threadIdx.x;
    const int head = t >> 6, lane = t & 63;

    xs[t] = x[i * DD + t];
    __syncthreads();

    const float* Wp = W + head * (DD * DHH) + lane;   // W[h][d][dh], lanes->dh coalesced
    float acc = 0.f;
    #pragma unroll 8
    for (int d = 0; d < DD; ++d)
        acc = fmaf(xs[d], Wp[d * DHH], acc);

    hb[i * (HH * DHH) + head * DHH + lane] = __float2bfloat16(acc);

    float vs = acc * a_src[head * DHH + lane];
    float vd = acc * a_dst[head * DHH + lane];
    #pragma unroll
    for (int off = 32; off; off >>= 1) {
        vs += __shfl_xor(vs, off, 64);
        vd += __shfl_xor(vd, off, 64);
    }
    if (lane == 0) {
        esrc[i * HH + head] = vs;
        edst[i * HH + head] = vd;
    }
}

// ---------------------------------------------------------------------------
// Kernel B: per-row edge lists (duplicates kept; deduped at use).
// Edge survives iff edge_vals > 0: sigmoid(mlp) > 0 strictly in fp32, so the
// W1/b1/W2/b2 MLP cannot zero an edge -- dead w.r.t. the output mask adj>0.
// ---------------------------------------------------------------------------
__global__ void edges_kernel(const int* __restrict__ ei, const float* __restrict__ ev,
                             int* __restrict__ cnt, unsigned short* __restrict__ lists)
{
    int e = blockIdx.x * blockDim.x + threadIdx.x;
    if (e >= EDGES) return;
    if (!(ev[e] > 0.f)) return;
    int r = ei[e];            // edge_index[0][e] = row
    int c = ei[EDGES + e];    // edge_index[1][e] = col
    int pos = atomicAdd(&cnt[r], 1);
    if (pos < CAP) lists[r * CAP + pos] = (unsigned short)c;
}

// ---------------------------------------------------------------------------
// Kernel C: block = row i. Phase A: LDS bitmask dedups the row's edge list
// (== reference's .at[row,col].set mask), compact to nbr[]. Phase B: wave =
// head; 3-pass masked softmax + PV. expf(NEG - m) == 0 exactly in fp32, so
// the sparse softmax equals the dense reference for deg > 0; deg == 0 ->
// softmax(all NEG) = uniform over all N columns.
// ---------------------------------------------------------------------------
__global__ __launch_bounds__(256) void attn_kernel(
    const int* __restrict__ cnt, const unsigned short* __restrict__ lists,
    const bf16* __restrict__ hb, const float* __restrict__ esrc,
    const float* __restrict__ edst, float* __restrict__ out)
{
    __shared__ unsigned int bm[NN / 32];   // 128 words: column bitmask for this row
    __shared__ int nbr[CAP];
    __shared__ int ndeg;
    const int i = blockIdx.x, t = threadIdx.x;
    const int head = t >> 6, lane = t & 63;

    if (t < NN / 32) bm[t] = 0;
    if (t == 0) ndeg = 0;
    __syncthreads();

    const int m = min(cnt[i], CAP);
    for (int k = t; k < m; k += 256) {
        int c = lists[i * CAP + k];
        atomicOr(&bm[c >> 5], 1u << (c & 31));
    }
    __syncthreads();

    if (t < NN / 32) {
        unsigned int bits = bm[t];
        while (bits) {
            int b = __ffs(bits) - 1;
            bits &= bits - 1;
            nbr[atomicAdd(&ndeg, 1)] = t * 32 + b;
        }
    }
    __syncthreads();

    const int deg = ndeg;
    float acc = 0.f;

    if (deg == 0) {
        for (int j = 0; j < NN; ++j)
            acc += __bfloat162float(hb[j * (HH * DHH) + head * DHH + lane]);
        acc *= (1.f / NN);
    } else {
        const float es_i = esrc[i * HH + head];
        // pass 1: max
        float mx = -INFINITY;
        for (int k = lane; k < deg; k += 64) {
            float e = es_i + edst[nbr[k] * HH + head];
            e = e > 0.f ? e : LRELU_ALPHA * e;
            mx = fmaxf(mx, e);
        }
        #pragma unroll
        for (int off = 32; off; off >>= 1) mx = fmaxf(mx, __shfl_xor(mx, off, 64));
        // pass 2: sum exp
        float s = 0.f;
        for (int k = lane; k < deg; k += 64) {
            float e = es_i + edst[nbr[k] * HH + head];
            e = e > 0.f ? e : LRELU_ALPHA * e;
            s += expf(e - mx);
        }
        #pragma unroll
        for (int off = 32; off; off >>= 1) s += __shfl_xor(s, off, 64);
        const float inv = 1.f / s;
        // pass 3: weighted accumulate; lane = dh, scalar weight per neighbor
        for (int k = 0; k < deg; ++k) {
            int j = nbr[k];
            float e = es_i + edst[j * HH + head];
            e = e > 0.f ? e : LRELU_ALPHA * e;
            float w = expf(e - mx) * inv;
            acc = fmaf(w, __bfloat162float(hb[j * (HH * DHH) + head * DHH + lane]), acc);
        }
    }
    // OUTPUT IS FP32 (this was the round-2/3 bug: bf16 written to float buffer)
    out[i * (HH * DHH) + head * DHH + lane] = acc;
}

// ---------------------------------------------------------------------------
extern "C" void kernel_launch(void* const* d_in, const int* in_sizes, int n_in,
                              void* d_out, int out_size, void* d_ws, size_t ws_size,
                              hipStream_t stream)
{
    const float* x     = (const float*)d_in[0];
    const float* ev    = (const float*)d_in[1];
    // d_in[2..5] = W1,b1,W2,b2 (edge MLP) -- provably irrelevant to the output
    const float* W     = (const float*)d_in[6];
    const float* a_src = (const float*)d_in[7];
    const float* a_dst = (const float*)d_in[8];
    const int*   ei    = (const int*)d_in[9];
    float* out = (float*)d_out;

    char* ws = (char*)d_ws;
    bf16*  hb    = (bf16*)ws;                                  // 2 MB
    float* esrc  = (float*)(ws + 2097152);                     // 64 KB
    float* edst  = (float*)(ws + 2162688);                     // 64 KB
    int*   cnt   = (int*)(ws + 2228224);                       // 16 KB
    unsigned short* lists = (unsigned short*)(ws + 2244608);   // 1 MB

    hipMemsetAsync(cnt, 0, NN * sizeof(int), stream);

    hproj_kernel<<<NN, 256, 0, stream>>>(x, W, a_src, a_dst, hb, esrc, edst);
    edges_kernel<<<(EDGES + 255) / 256, 256, 0, stream>>>(ei, ev, cnt, lists);
    attn_kernel<<<NN, 256, 0, stream>>>(cnt, lists, hb, esrc, edst, out);
}

// Round 5
// 130.629 us; speedup vs baseline: 1.1404x; 1.1404x over previous
//
#include <hip/hip_runtime.h>
#include <hip/hip_bf16.h>

// Problem constants (from reference)
#define NN    4096
#define DD    256
#define HH    4
#define DHH   64
#define EDGES 131072
#define CAP   128           // per-row edge-list capacity; deg ~ Poisson(32), P(>128) < 1e-40
#define NB    8             // nodes per hproj block: W reuse x8, ILP x8
#define LRELU_ALPHA 0.2f

typedef __hip_bfloat16 bf16;

// dtypes (validated round 4): all float inputs fp32, edge_index int32, OUTPUT fp32.
//
// ws layout, 3.14 MB total:
//   hb    [N][H][DH] bf16   @ 0         (2 MB)
//   esrc  [N][H]     f32    @ 2097152   (64 KB)
//   edst  [N][H]     f32    @ 2162688   (64 KB)
//   cnt   [N]        int    @ 2228224   (16 KB)   <- zeroed inside hproj
//   lists [N][CAP]   ushort @ 2244608   (1 MB)

// ---------------------------------------------------------------------------
// Kernel A: h[n,h,dh] = sum_d x[n,d] W[h,d,dh]  (fp32 acc, stored bf16)
//           esrc[n,h] = sum_dh h*a_src[h,dh] ; edst likewise (fp32, from regs)
// Round-4 version re-read full W per node (1 GB L2 -> 29 us floor, 43 us
// measured, VALUBusy 22%). Now: block = 8 nodes, W element reused across 8
// fp32 accumulators (W traffic /8, ILP 8 kills the serial-fmaf chain).
// Accumulation order per node is unchanged -> bit-identical to round 4.
// ---------------------------------------------------------------------------
__global__ __launch_bounds__(256, 2) void hproj_kernel(
    const float* __restrict__ x, const float* __restrict__ W,
    const float* __restrict__ a_src, const float* __restrict__ a_dst,
    bf16* __restrict__ hb, float* __restrict__ esrc, float* __restrict__ edst,
    int* __restrict__ cnt)
{
    __shared__ float xs[NB][DD];
    const int i0 = blockIdx.x * NB;
    const int t  = threadIdx.x;

    // 8 node rows are contiguous in x: one 8 KB flat float4 copy
    {
        const float4* src = (const float4*)(x + (size_t)i0 * DD);
        float4* dst = (float4*)&xs[0][0];
        #pragma unroll
        for (int k = 0; k < (NB * DD / 4) / 256; ++k)
            dst[t + k * 256] = src[t + k * 256];
    }
    // zero per-row edge counters here (hproj completes before edges_kernel)
    if (t < NB) cnt[i0 + t] = 0;
    __syncthreads();

    const int head = t >> 6, lane = t & 63;
    const float* Wp = W + head * (DD * DHH) + lane;  // lanes -> dh: coalesced

    float acc[NB];
    #pragma unroll
    for (int n = 0; n < NB; ++n) acc[n] = 0.f;

    for (int d = 0; d < DD; d += 8) {
        float w[8];
        #pragma unroll
        for (int u = 0; u < 8; ++u) w[u] = Wp[(d + u) * DHH];
        #pragma unroll
        for (int u = 0; u < 8; ++u) {
            #pragma unroll
            for (int n = 0; n < NB; ++n)
                acc[n] = fmaf(xs[n][d + u], w[u], acc[n]);   // LDS broadcast
        }
    }

    #pragma unroll
    for (int n = 0; n < NB; ++n)
        hb[(size_t)(i0 + n) * (HH * DHH) + t] = __float2bfloat16(acc[n]);

    const float as = a_src[head * DHH + lane];
    const float ad = a_dst[head * DHH + lane];
    #pragma unroll
    for (int n = 0; n < NB; ++n) {
        float vs = acc[n] * as, vd = acc[n] * ad;
        #pragma unroll
        for (int off = 32; off; off >>= 1) {
            vs += __shfl_xor(vs, off, 64);
            vd += __shfl_xor(vd, off, 64);
        }
        if (lane == 0) {
            esrc[(i0 + n) * HH + head] = vs;
            edst[(i0 + n) * HH + head] = vd;
        }
    }
}

// ---------------------------------------------------------------------------
// Kernel B: per-row edge lists (duplicates kept; deduped at use).
// Edge survives iff edge_vals > 0: sigmoid(mlp) > 0 strictly in fp32, so the
// W1/b1/W2/b2 MLP cannot zero an edge -- dead w.r.t. the output mask adj>0.
// ---------------------------------------------------------------------------
__global__ void edges_kernel(const int* __restrict__ ei, const float* __restrict__ ev,
                             int* __restrict__ cnt, unsigned short* __restrict__ lists)
{
    int e = blockIdx.x * blockDim.x + threadIdx.x;
    if (e >= EDGES) return;
    if (!(ev[e] > 0.f)) return;
    int r = ei[e];            // edge_index[0][e] = row
    int c = ei[EDGES + e];    // edge_index[1][e] = col
    int pos = atomicAdd(&cnt[r], 1);
    if (pos < CAP) lists[r * CAP + pos] = (unsigned short)c;
}

// ---------------------------------------------------------------------------
// Kernel C: block = row i. Phase A: LDS bitmask dedups the row's edge list
// (== reference's .at[row,col].set mask), compact to nbr[]. Phase B: wave =
// head; 3-pass masked softmax + PV. expf(NEG - m) == 0 exactly in fp32, so
// the sparse softmax equals the dense reference for deg > 0; deg == 0 ->
// softmax(all NEG) = uniform over all N columns.
// ---------------------------------------------------------------------------
__global__ __launch_bounds__(256) void attn_kernel(
    const int* __restrict__ cnt, const unsigned short* __restrict__ lists,
    const bf16* __restrict__ hb, const float* __restrict__ esrc,
    const float* __restrict__ edst, float* __restrict__ out)
{
    __shared__ unsigned int bm[NN / 32];   // 128 words: column bitmask for this row
    __shared__ int nbr[CAP];
    __shared__ int ndeg;
    const int i = blockIdx.x, t = threadIdx.x;
    const int head = t >> 6, lane = t & 63;

    if (t < NN / 32) bm[t] = 0;
    if (t == 0) ndeg = 0;
    __syncthreads();

    const int m = min(cnt[i], CAP);
    for (int k = t; k < m; k += 256) {
        int c = lists[i * CAP + k];
        atomicOr(&bm[c >> 5], 1u << (c & 31));
    }
    __syncthreads();

    if (t < NN / 32) {
        unsigned int bits = bm[t];
        while (bits) {
            int b = __ffs(bits) - 1;
            bits &= bits - 1;
            nbr[atomicAdd(&ndeg, 1)] = t * 32 + b;
        }
    }
    __syncthreads();

    const int deg = ndeg;
    float acc = 0.f;

    if (deg == 0) {
        for (int j = 0; j < NN; ++j)
            acc += __bfloat162float(hb[j * (HH * DHH) + head * DHH + lane]);
        acc *= (1.f / NN);
    } else {
        const float es_i = esrc[i * HH + head];
        // pass 1: max
        float mx = -INFINITY;
        for (int k = lane; k < deg; k += 64) {
            float e = es_i + edst[nbr[k] * HH + head];
            e = e > 0.f ? e : LRELU_ALPHA * e;
            mx = fmaxf(mx, e);
        }
        #pragma unroll
        for (int off = 32; off; off >>= 1) mx = fmaxf(mx, __shfl_xor(mx, off, 64));
        // pass 2: sum exp
        float s = 0.f;
        for (int k = lane; k < deg; k += 64) {
            float e = es_i + edst[nbr[k] * HH + head];
            e = e > 0.f ? e : LRELU_ALPHA * e;
            s += expf(e - mx);
        }
        #pragma unroll
        for (int off = 32; off; off >>= 1) s += __shfl_xor(s, off, 64);
        const float inv = 1.f / s;
        // pass 3: weighted accumulate; lane = dh, scalar weight per neighbor
        for (int k = 0; k < deg; ++k) {
            int j = nbr[k];
            float e = es_i + edst[j * HH + head];
            e = e > 0.f ? e : LRELU_ALPHA * e;
            float w = expf(e - mx) * inv;
            acc = fmaf(w, __bfloat162float(hb[j * (HH * DHH) + head * DHH + lane]), acc);
        }
    }
    out[i * (HH * DHH) + head * DHH + lane] = acc;   // fp32 output
}

// ---------------------------------------------------------------------------
extern "C" void kernel_launch(void* const* d_in, const int* in_sizes, int n_in,
                              void* d_out, int out_size, void* d_ws, size_t ws_size,
                              hipStream_t stream)
{
    const float* x     = (const float*)d_in[0];
    const float* ev    = (const float*)d_in[1];
    // d_in[2..5] = W1,b1,W2,b2 (edge MLP) -- provably irrelevant to the output
    const float* W     = (const float*)d_in[6];
    const float* a_src = (const float*)d_in[7];
    const float* a_dst = (const float*)d_in[8];
    const int*   ei    = (const int*)d_in[9];
    float* out = (float*)d_out;

    char* ws = (char*)d_ws;
    bf16*  hb    = (bf16*)ws;                                  // 2 MB
    float* esrc  = (float*)(ws + 2097152);                     // 64 KB
    float* edst  = (float*)(ws + 2162688);                     // 64 KB
    int*   cnt   = (int*)(ws + 2228224);                       // 16 KB
    unsigned short* lists = (unsigned short*)(ws + 2244608);   // 1 MB

    hproj_kernel<<<NN / NB, 256, 0, stream>>>(x, W, a_src, a_dst, hb, esrc, edst, cnt);
    edges_kernel<<<(EDGES + 255) / 256, 256, 0, stream>>>(ei, ev, cnt, lists);
    attn_kernel<<<NN, 256, 0, stream>>>(cnt, lists, hb, esrc, edst, out);
}

// Round 6
// 115.391 us; speedup vs baseline: 1.2910x; 1.1321x over previous
//
#include <hip/hip_runtime.h>
#include <hip/hip_bf16.h>

// Problem constants (from reference)
#define NN    4096
#define DD    256
#define HH    4
#define DHH   64
#define EDGES 131072
#define CAP   128           // per-row edge-list capacity; deg ~ Poisson(32), P(>128) < 1e-40
#define NB    8             // nodes per hproj block: W reuse x8, ILP x8
#define LRELU_ALPHA 0.2f

typedef __hip_bfloat16 bf16;

// dtypes (validated round 4): all float inputs fp32, edge_index int32, OUTPUT fp32.
// Harness floor (round-5 profile): 256 MiB d_ws 0xAA re-poison fill runs at
// 6.3 TB/s ~= 42 us in-stream before our kernels -- untouchable.
//
// ws layout, 3.14 MB total:
//   hb    [N][H][DH] bf16   @ 0         (2 MB)
//   esrc  [N][H]     f32    @ 2097152   (64 KB)
//   edst  [N][H]     f32    @ 2162688   (64 KB)
//   cnt   [N]        int    @ 2228224   (16 KB)   <- zeroed inside hproj
//   lists [N][CAP]   ushort @ 2244608   (1 MB)

// ---------------------------------------------------------------------------
// Kernel A: h[n,h,dh] = sum_d x[n,d] W[h,d,dh]  (fp32 acc, stored bf16)
//           esrc[n,h] = sum_dh h*a_src[h,dh] ; edst likewise
// Round-5 inner loop paid 1 scalar ds_read per fmaf (4.2M ds instrs). Now:
// float4 LDS reads (ds_read_b128, count /4) + 4-wide W load batches.
// Per-node accumulation order still d-ascending -> bit-identical hb/esrc/edst.
// ---------------------------------------------------------------------------
__global__ __launch_bounds__(256, 2) void hproj_kernel(
    const float* __restrict__ x, const float* __restrict__ W,
    const float* __restrict__ a_src, const float* __restrict__ a_dst,
    bf16* __restrict__ hb, float* __restrict__ esrc, float* __restrict__ edst,
    int* __restrict__ cnt)
{
    __shared__ float xs[NB][DD];
    const int i0 = blockIdx.x * NB;
    const int t  = threadIdx.x;

    // 8 node rows are contiguous in x: one 8 KB flat float4 copy
    {
        const float4* src = (const float4*)(x + (size_t)i0 * DD);
        float4* dst = (float4*)&xs[0][0];
        #pragma unroll
        for (int k = 0; k < (NB * DD / 4) / 256; ++k)
            dst[t + k * 256] = src[t + k * 256];
    }
    // zero per-row edge counters here (hproj completes before edges_kernel)
    if (t < NB) cnt[i0 + t] = 0;
    __syncthreads();

    const int head = t >> 6, lane = t & 63;
    const float* Wp = W + head * (DD * DHH) + lane;  // lanes -> dh: coalesced

    float acc[NB];
    #pragma unroll
    for (int n = 0; n < NB; ++n) acc[n] = 0.f;

    #pragma unroll 4
    for (int d = 0; d < DD; d += 4) {
        const float w0 = Wp[(d + 0) * DHH];
        const float w1 = Wp[(d + 1) * DHH];
        const float w2 = Wp[(d + 2) * DHH];
        const float w3 = Wp[(d + 3) * DHH];
        #pragma unroll
        for (int n = 0; n < NB; ++n) {
            const float4 xv = *(const float4*)&xs[n][d];   // one ds_read_b128
            acc[n] = fmaf(xv.x, w0, acc[n]);
            acc[n] = fmaf(xv.y, w1, acc[n]);
            acc[n] = fmaf(xv.z, w2, acc[n]);
            acc[n] = fmaf(xv.w, w3, acc[n]);
        }
    }

    #pragma unroll
    for (int n = 0; n < NB; ++n)
        hb[(size_t)(i0 + n) * (HH * DHH) + t] = __float2bfloat16(acc[n]);

    const float as = a_src[head * DHH + lane];
    const float ad = a_dst[head * DHH + lane];
    #pragma unroll
    for (int n = 0; n < NB; ++n) {
        float vs = acc[n] * as, vd = acc[n] * ad;
        #pragma unroll
        for (int off = 32; off; off >>= 1) {
            vs += __shfl_xor(vs, off, 64);
            vd += __shfl_xor(vd, off, 64);
        }
        if (lane == 0) {
            esrc[(i0 + n) * HH + head] = vs;
            edst[(i0 + n) * HH + head] = vd;
        }
    }
}

// ---------------------------------------------------------------------------
// Kernel B: per-row edge lists (duplicates kept; deduped at use).
// Edge survives iff edge_vals > 0: sigmoid(mlp) > 0 strictly in fp32, so the
// W1/b1/W2/b2 MLP cannot zero an edge -- dead w.r.t. the output mask adj>0.
// ---------------------------------------------------------------------------
__global__ void edges_kernel(const int* __restrict__ ei, const float* __restrict__ ev,
                             int* __restrict__ cnt, unsigned short* __restrict__ lists)
{
    int e = blockIdx.x * blockDim.x + threadIdx.x;
    if (e >= EDGES) return;
    if (!(ev[e] > 0.f)) return;
    int r = ei[e];            // edge_index[0][e] = row
    int c = ei[EDGES + e];    // edge_index[1][e] = col
    int pos = atomicAdd(&cnt[r], 1);
    if (pos < CAP) lists[r * CAP + pos] = (unsigned short)c;
}

// ---------------------------------------------------------------------------
// Kernel C: block = row i. Phase A: LDS bitmask dedups the row's edge list
// (== reference's .at[row,col].set mask), compact to nbr[]. Phase B: wave =
// head. Round-5 recomputed expf + edst gather per neighbor in every pass in
// all 64 lanes; now logits are cached in LDS (pass 1), exponentiated in
// place (pass 2), and pass 3 is a lean 2x-unrolled w*h accumulation with
// LDS-broadcast weights. expf(NEG-m)==0 exactly in fp32 -> sparse softmax
// equals the dense reference (deg>0); deg==0 -> uniform over all N columns.
// ---------------------------------------------------------------------------
__global__ __launch_bounds__(256) void attn_kernel(
    const int* __restrict__ cnt, const unsigned short* __restrict__ lists,
    const bf16* __restrict__ hb, const float* __restrict__ esrc,
    const float* __restrict__ edst, float* __restrict__ out)
{
    __shared__ unsigned int bm[NN / 32];   // 128 words: column bitmask for this row
    __shared__ int nbr[CAP];
    __shared__ float wts[HH][CAP];         // per-head logits -> weights (2 KB)
    __shared__ int ndeg;
    const int i = blockIdx.x, t = threadIdx.x;
    const int head = t >> 6, lane = t & 63;

    if (t < NN / 32) bm[t] = 0;
    if (t == 0) ndeg = 0;
    __syncthreads();

    const int m = min(cnt[i], CAP);
    for (int k = t; k < m; k += 256) {
        int c = lists[i * CAP + k];
        atomicOr(&bm[c >> 5], 1u << (c & 31));
    }
    __syncthreads();

    if (t < NN / 32) {
        unsigned int bits = bm[t];
        while (bits) {
            int b = __ffs(bits) - 1;
            bits &= bits - 1;
            nbr[atomicAdd(&ndeg, 1)] = t * 32 + b;
        }
    }
    __syncthreads();

    const int deg = ndeg;
    float acc = 0.f;

    if (deg == 0) {
        for (int j = 0; j < NN; ++j)
            acc += __bfloat162float(hb[j * (HH * DHH) + t]);
        acc *= (1.f / NN);
    } else {
        const float es_i = esrc[i * HH + head];
        // pass 1: logits -> LDS, wave-reduce max (wave-synchronous per head)
        float mx = -INFINITY;
        for (int k = lane; k < deg; k += 64) {
            float e = es_i + edst[nbr[k] * HH + head];
            e = e > 0.f ? e : LRELU_ALPHA * e;
            wts[head][k] = e;
            mx = fmaxf(mx, e);
        }
        #pragma unroll
        for (int off = 32; off; off >>= 1) mx = fmaxf(mx, __shfl_xor(mx, off, 64));
        // pass 2: exponentiate in place, wave-reduce sum
        float s = 0.f;
        for (int k = lane; k < deg; k += 64) {
            float w = expf(wts[head][k] - mx);
            wts[head][k] = w;
            s += w;
        }
        #pragma unroll
        for (int off = 32; off; off >>= 1) s += __shfl_xor(s, off, 64);
        // pass 3: acc = sum_k w_k * h[j_k][t]; normalize once at the end
        int k = 0;
        for (; k + 1 < deg; k += 2) {
            const int j0 = nbr[k], j1 = nbr[k + 1];
            const float w0 = wts[head][k], w1 = wts[head][k + 1];
            const float h0 = __bfloat162float(hb[(size_t)j0 * (HH * DHH) + t]);
            const float h1 = __bfloat162float(hb[(size_t)j1 * (HH * DHH) + t]);
            acc = fmaf(w0, h0, acc);
            acc = fmaf(w1, h1, acc);
        }
        if (k < deg)
            acc = fmaf(wts[head][k],
                       __bfloat162float(hb[(size_t)nbr[k] * (HH * DHH) + t]), acc);
        acc *= (1.f / s);
    }
    out[i * (HH * DHH) + t] = acc;   // fp32 output
}

// ---------------------------------------------------------------------------
extern "C" void kernel_launch(void* const* d_in, const int* in_sizes, int n_in,
                              void* d_out, int out_size, void* d_ws, size_t ws_size,
                              hipStream_t stream)
{
    const float* x     = (const float*)d_in[0];
    const float* ev    = (const float*)d_in[1];
    // d_in[2..5] = W1,b1,W2,b2 (edge MLP) -- provably irrelevant to the output
    const float* W     = (const float*)d_in[6];
    const float* a_src = (const float*)d_in[7];
    const float* a_dst = (const float*)d_in[8];
    const int*   ei    = (const int*)d_in[9];
    float* out = (float*)d_out;

    char* ws = (char*)d_ws;
    bf16*  hb    = (bf16*)ws;                                  // 2 MB
    float* esrc  = (float*)(ws + 2097152);                     // 64 KB
    float* edst  = (float*)(ws + 2162688);                     // 64 KB
    int*   cnt   = (int*)(ws + 2228224);                       // 16 KB
    unsigned short* lists = (unsigned short*)(ws + 2244608);   // 1 MB

    hproj_kernel<<<NN / NB, 256, 0, stream>>>(x, W, a_src, a_dst, hb, esrc, edst, cnt);
    edges_kernel<<<(EDGES + 255) / 256, 256, 0, stream>>>(ei, ev, cnt, lists);
    attn_kernel<<<NN, 256, 0, stream>>>(cnt, lists, hb, esrc, edst, out);
}

// Round 7
// 113.500 us; speedup vs baseline: 1.3125x; 1.0167x over previous
//
#include <hip/hip_runtime.h>
#include <hip/hip_bf16.h>

// Problem constants (from reference)
#define NN    4096
#define DD    256
#define HH    4
#define DHH   64
#define EDGES 131072
#define CAP   128           // per-row edge-list capacity; deg ~ Poisson(32), P(>128) < 1e-40
#define NB    8             // nodes per hproj block: W reuse x8, ILP x8
#define LRELU_ALPHA 0.2f

typedef __hip_bfloat16 bf16;

// dtypes (validated round 4): all float inputs fp32, edge_index int32, OUTPUT fp32.
// Harness floor: 256 MiB d_ws 0xAA re-poison fill runs at ~6.3 TB/s ~= 42 us
// in-stream before our kernels (round-5/6 profiles) -- untouchable.
//
// ws layout, 3.14 MB total:
//   hb    [N][H][DH] bf16   @ 0         (2 MB)
//   esrc  [N][H]     f32    @ 2097152   (64 KB)
//   edst  [N][H]     f32    @ 2162688   (64 KB)
//   cnt   [N]        int    @ 2228224   (16 KB)   <- hipMemsetAsync node
//   lists [N][CAP]   ushort @ 2244608   (1 MB)

// ---------------------------------------------------------------------------
// Kernel A (fused): hproj for 8 nodes/block + a 256-edge slice/block.
//   grid = NN/NB = 512 = EDGES/256, so one launch covers both exactly.
//   cnt is pre-zeroed by a memset node -> no zero/atomic race across blocks.
// h[n,h,dh] = sum_d x[n,d] W[h,d,dh] (fp32 acc, stored bf16); esrc/edst from
// fp32 regs. Edge survives iff edge_vals > 0 (sigmoid(mlp) > 0 strictly in
// fp32, so the W1/b1/W2/b2 MLP is dead w.r.t. the adj>0 mask).
// Accumulation order d-ascending -> hb/esrc/edst bit-identical to round 6.
// ---------------------------------------------------------------------------
__global__ __launch_bounds__(256, 2) void hproj_edges_kernel(
    const float* __restrict__ x, const float* __restrict__ W,
    const float* __restrict__ a_src, const float* __restrict__ a_dst,
    const int* __restrict__ ei, const float* __restrict__ ev,
    bf16* __restrict__ hb, float* __restrict__ esrc, float* __restrict__ edst,
    int* __restrict__ cnt, unsigned short* __restrict__ lists)
{
    __shared__ float xs[NB][DD];
    const int i0 = blockIdx.x * NB;
    const int t  = threadIdx.x;

    // stage 8 contiguous node rows of x: one 8 KB flat float4 copy
    {
        const float4* src = (const float4*)(x + (size_t)i0 * DD);
        float4* dst = (float4*)&xs[0][0];
        #pragma unroll
        for (int k = 0; k < (NB * DD / 4) / 256; ++k)
            dst[t + k * 256] = src[t + k * 256];
    }

    // edge slice: one edge per thread (hidden under the FMA phase's waves)
    {
        const int e = blockIdx.x * 256 + t;
        if (ev[e] > 0.f) {
            const int r = ei[e];            // edge_index[0][e]
            const int c = ei[EDGES + e];    // edge_index[1][e]
            const int pos = atomicAdd(&cnt[r], 1);
            if (pos < CAP) lists[r * CAP + pos] = (unsigned short)c;
        }
    }
    __syncthreads();

    const int head = t >> 6, lane = t & 63;
    const float* Wp = W + head * (DD * DHH) + lane;  // lanes -> dh: coalesced

    float acc[NB];
    #pragma unroll
    for (int n = 0; n < NB; ++n) acc[n] = 0.f;

    #pragma unroll 4
    for (int d = 0; d < DD; d += 4) {
        const float w0 = Wp[(d + 0) * DHH];
        const float w1 = Wp[(d + 1) * DHH];
        const float w2 = Wp[(d + 2) * DHH];
        const float w3 = Wp[(d + 3) * DHH];
        #pragma unroll
        for (int n = 0; n < NB; ++n) {
            const float4 xv = *(const float4*)&xs[n][d];   // LDS broadcast b128
            acc[n] = fmaf(xv.x, w0, acc[n]);
            acc[n] = fmaf(xv.y, w1, acc[n]);
            acc[n] = fmaf(xv.z, w2, acc[n]);
            acc[n] = fmaf(xv.w, w3, acc[n]);
        }
    }

    #pragma unroll
    for (int n = 0; n < NB; ++n)
        hb[(size_t)(i0 + n) * (HH * DHH) + t] = __float2bfloat16(acc[n]);

    const float as = a_src[head * DHH + lane];
    const float ad = a_dst[head * DHH + lane];
    #pragma unroll
    for (int n = 0; n < NB; ++n) {
        float vs = acc[n] * as, vd = acc[n] * ad;
        #pragma unroll
        for (int off = 32; off; off >>= 1) {
            vs += __shfl_xor(vs, off, 64);
            vd += __shfl_xor(vd, off, 64);
        }
        if (lane == 0) {
            esrc[(i0 + n) * HH + head] = vs;
            edst[(i0 + n) * HH + head] = vd;
        }
    }
}

// ---------------------------------------------------------------------------
// Kernel B: block = row i. Phase A: LDS bitmask dedups the row's edge list
// (== reference's .at[row,col].set mask), compact to nbr[]. Phase B: wave =
// head; logits cached in LDS, exponentiated in place, then a 4x-unrolled PV
// loop with grouped independent loads (4 L2 loads in flight per wait).
// fmaf chain stays k-ascending -> bit-identical to round 6.
// expf(NEG-m)==0 exactly in fp32 -> sparse softmax == dense reference
// (deg>0); deg==0 -> uniform over all N columns.
// ---------------------------------------------------------------------------
__global__ __launch_bounds__(256) void attn_kernel(
    const int* __restrict__ cnt, const unsigned short* __restrict__ lists,
    const bf16* __restrict__ hb, const float* __restrict__ esrc,
    const float* __restrict__ edst, float* __restrict__ out)
{
    __shared__ unsigned int bm[NN / 32];   // 128 words: column bitmask for this row
    __shared__ int nbr[CAP];
    __shared__ float wts[HH][CAP];         // per-head logits -> weights (2 KB)
    __shared__ int ndeg;
    const int i = blockIdx.x, t = threadIdx.x;
    const int head = t >> 6, lane = t & 63;

    if (t < NN / 32) bm[t] = 0;
    if (t == 0) ndeg = 0;
    __syncthreads();

    const int m = min(cnt[i], CAP);
    for (int k = t; k < m; k += 256) {
        int c = lists[i * CAP + k];
        atomicOr(&bm[c >> 5], 1u << (c & 31));
    }
    __syncthreads();

    if (t < NN / 32) {
        unsigned int bits = bm[t];
        while (bits) {
            int b = __ffs(bits) - 1;
            bits &= bits - 1;
            nbr[atomicAdd(&ndeg, 1)] = t * 32 + b;
        }
    }
    __syncthreads();

    const int deg = ndeg;
    float acc = 0.f;

    if (deg == 0) {
        for (int j = 0; j < NN; ++j)
            acc += __bfloat162float(hb[j * (HH * DHH) + t]);
        acc *= (1.f / NN);
    } else {
        const float es_i = esrc[i * HH + head];
        // pass 1: logits -> LDS, wave-reduce max (wave-synchronous per head)
        float mx = -INFINITY;
        for (int k = lane; k < deg; k += 64) {
            float e = es_i + edst[nbr[k] * HH + head];
            e = e > 0.f ? e : LRELU_ALPHA * e;
            wts[head][k] = e;
            mx = fmaxf(mx, e);
        }
        #pragma unroll
        for (int off = 32; off; off >>= 1) mx = fmaxf(mx, __shfl_xor(mx, off, 64));
        // pass 2: exponentiate in place, wave-reduce sum
        float s = 0.f;
        for (int k = lane; k < deg; k += 64) {
            float w = expf(wts[head][k] - mx);
            wts[head][k] = w;
            s += w;
        }
        #pragma unroll
        for (int off = 32; off; off >>= 1) s += __shfl_xor(s, off, 64);
        // pass 3: acc = sum_k w_k * h[j_k][t]; 4 independent loads per batch
        int k = 0;
        for (; k + 3 < deg; k += 4) {
            const int j0 = nbr[k], j1 = nbr[k + 1], j2 = nbr[k + 2], j3 = nbr[k + 3];
            const float w0 = wts[head][k],     w1 = wts[head][k + 1];
            const float w2 = wts[head][k + 2], w3 = wts[head][k + 3];
            const float h0 = __bfloat162float(hb[(size_t)j0 * (HH * DHH) + t]);
            const float h1 = __bfloat162float(hb[(size_t)j1 * (HH * DHH) + t]);
            const float h2 = __bfloat162float(hb[(size_t)j2 * (HH * DHH) + t]);
            const float h3 = __bfloat162float(hb[(size_t)j3 * (HH * DHH) + t]);
            acc = fmaf(w0, h0, acc);
            acc = fmaf(w1, h1, acc);
            acc = fmaf(w2, h2, acc);
            acc = fmaf(w3, h3, acc);
        }
        for (; k < deg; ++k)
            acc = fmaf(wts[head][k],
                       __bfloat162float(hb[(size_t)nbr[k] * (HH * DHH) + t]), acc);
        acc *= (1.f / s);
    }
    out[i * (HH * DHH) + t] = acc;   // fp32 output
}

// ---------------------------------------------------------------------------
extern "C" void kernel_launch(void* const* d_in, const int* in_sizes, int n_in,
                              void* d_out, int out_size, void* d_ws, size_t ws_size,
                              hipStream_t stream)
{
    const float* x     = (const float*)d_in[0];
    const float* ev    = (const float*)d_in[1];
    // d_in[2..5] = W1,b1,W2,b2 (edge MLP) -- provably irrelevant to the output
    const float* W     = (const float*)d_in[6];
    const float* a_src = (const float*)d_in[7];
    const float* a_dst = (const float*)d_in[8];
    const int*   ei    = (const int*)d_in[9];
    float* out = (float*)d_out;

    char* ws = (char*)d_ws;
    bf16*  hb    = (bf16*)ws;                                  // 2 MB
    float* esrc  = (float*)(ws + 2097152);                     // 64 KB
    float* edst  = (float*)(ws + 2162688);                     // 64 KB
    int*   cnt   = (int*)(ws + 2228224);                       // 16 KB
    unsigned short* lists = (unsigned short*)(ws + 2244608);   // 1 MB

    hipMemsetAsync(cnt, 0, NN * sizeof(int), stream);
    hproj_edges_kernel<<<NN / NB, 256, 0, stream>>>(x, W, a_src, a_dst, ei, ev,
                                                    hb, esrc, edst, cnt, lists);
    attn_kernel<<<NN, 256, 0, stream>>>(cnt, lists, hb, esrc, edst, out);
}